// Round 12
// baseline (171.094 us; speedup 1.0000x reference)
//
#include <hip/hip_runtime.h>

using f32x4 = __attribute__((ext_vector_type(4))) float;
using s16x8 = __attribute__((ext_vector_type(8))) short;
using s16x4 = __attribute__((ext_vector_type(4))) short;

#define P_PIX 196
#define NPIX_ALL (128 * 196)   // 25088
#define NROW  208
#define KT    32               // shorts per LDS row = 64 B = 4 chunks of 16 B

static __device__ __forceinline__ short f2bf(float f) {
  union { float f; unsigned u; } a; a.f = f;
  unsigned u = a.u;
  u += 0x7fffu + ((u >> 16) & 1u);   // RNE
  return (short)(u >> 16);
}

static __device__ __forceinline__ f32x4 mfma16(s16x8 a, s16x8 b, f32x4 c) {
  return __builtin_amdgcn_mfma_f32_16x16x32_bf16(a, b, c, 0, 0, 0);
}

static __device__ __forceinline__ void gload16(const short* g, short* l) {
  __builtin_amdgcn_global_load_lds(
      (const __attribute__((address_space(1))) unsigned int*)(g),
      (__attribute__((address_space(3))) unsigned int*)(l), 16, 0, 0);
}

// swizzled 16B-fragment pointer: chunk = l4 ^ ((row>>1)&3)
static __device__ __forceinline__ const s16x8* fragp(const short* buf, int row, int l4) {
  return (const s16x8*)(buf + row * KT + ((l4 ^ ((row >> 1) & 3)) << 3));
}

// stage rows x 32 shorts into LDS; dest linear, source chunk pre-swizzled.
static __device__ __forceinline__ void stage(const short* __restrict__ src, int srcK,
                                             int k0, short* dst, int rows, int rmax,
                                             int tid, int nthr) {
  for (int t = tid; t < rows * 4; t += nthr) {
    int r = t >> 2, c = t & 3;
    int rr = r < rmax ? r : rmax;
    int cs = c ^ ((r >> 1) & 3);
    gload16(src + (size_t)rr * srcK + k0 + cs * 8, dst + t * 8);
  }
}

// ---------------- merged prep: w1/w3 cvt, w2 transpose, bn fold ----------------

__global__ void k_prep(const float* __restrict__ w1, const float* __restrict__ w2,
                       const float* __restrict__ w3,
                       const float* g1, const float* b1, const float* m1, const float* v1,
                       const float* g2, const float* b2, const float* m2, const float* v2,
                       const float* g3, const float* b3, const float* m3, const float* v3,
                       float* bn, short* W1b, short* W2t, short* W3b) {
  int i = blockIdx.x * 256 + threadIdx.x;
  if (i < 65536) {
    f32x4 v = *(const f32x4*)(w1 + i * 4);
    s16x4 o;
    o[0] = f2bf(v[0]); o[1] = f2bf(v[1]); o[2] = f2bf(v[2]); o[3] = f2bf(v[3]);
    *(s16x4*)(W1b + i * 4) = o;
  } else if (i < 131072) {
    int q = i - 65536;
    f32x4 v = *(const f32x4*)(w3 + q * 4);
    s16x4 o;
    o[0] = f2bf(v[0]); o[1] = f2bf(v[1]); o[2] = f2bf(v[2]); o[3] = f2bf(v[3]);
    *(s16x4*)(W3b + q * 4) = o;
  } else if (i < 278528) {
    int q = (i - 131072) * 4;
    s16x4 o;
    #pragma unroll
    for (int k = 0; k < 4; ++k) {
      int idx = q + k;
      int s = idx >> 16, rem = idx & 65535;
      int co = rem >> 8, ci = rem & 255;
      o[k] = f2bf(w2[(co * 256 + ci) * 9 + s]);
    }
    *(s16x4*)(W2t + q) = o;
  } else if (i < 280064) {
    int t = i - 278528;
    if (t < 256) {
      float inv = g1[t] * rsqrtf(v1[t] + 1e-5f);
      bn[t] = inv; bn[256 + t] = b1[t] - m1[t] * inv;
    } else if (t < 512) {
      int c = t - 256;
      float inv = g2[c] * rsqrtf(v2[c] + 1e-5f);
      bn[512 + c] = inv; bn[768 + c] = b2[c] - m2[c] * inv;
    } else {
      int c = t - 512;
      float inv = g3[c] * rsqrtf(v3[c] + 1e-5f);
      bn[1024 + c] = inv; bn[2048 + c] = b3[c] - m3[c] * inv;
    }
  }
}

// ---------------- layer 1: 1x1, 1024->256, fused fp32-x transpose+cvt ----------------
// grid: n(128) x mb(2) x jh(2), XCD-swizzled. A-frags from global (W1 L2-resident).

__global__ __launch_bounds__(256) void k_layer1(
    const float* __restrict__ x, const short* __restrict__ W1b,
    const float* __restrict__ bnbuf, short* __restrict__ H1) {
  __shared__ __align__(16) short lB[2][128 * KT];
  const int tid = threadIdx.x;
  const int vb = (blockIdx.x & 7) * 64 + (blockIdx.x >> 3);   // XCD swizzle (512 blocks)
  const int n = vb >> 2, mb = (vb >> 1) & 1, jh = vb & 1;
  const int lane = tid & 63, wave = tid >> 6;
  const int l15 = lane & 15, l4 = lane >> 4;

  if (jh == 1 && tid < 96) {
    int bb = tid / 48, idx = tid % 48;
    s16x8 z = {0,0,0,0,0,0,0,0};
    *(s16x8*)(&lB[bb][100 * KT + idx * 8]) = z;
  }

  const float* xs = x + (size_t)n * 1024 * P_PIX;
  const short* Asrc = W1b + (size_t)(mb * 128) * 1024;

  const int npg = jh ? 25 : 28;
  const int pgbase = jh ? 24 : 0;
  const bool act = tid < npg * 8;
  const int pg = pgbase + (act ? tid % npg : 0);
  const int kg = act ? tid / npg : 0;
  const int lrow0 = pg * 4 - jh * 96;

  f32x4 rX[4], rY[4];
  auto loadx = [&](int kt, f32x4* r) {
    if (!act) return;
    const float* sp = xs + (size_t)(kt * 32 + kg * 4) * P_PIX + pg * 4;
    r[0] = *(const f32x4*)sp;
    r[1] = *(const f32x4*)(sp + P_PIX);
    r[2] = *(const f32x4*)(sp + 2 * P_PIX);
    r[3] = *(const f32x4*)(sp + 3 * P_PIX);
  };
  auto cvtw = [&](const f32x4* r, short* buf) {
    if (!act) return;
    int chunk = kg >> 1, inner = (kg & 1) * 4;
    #pragma unroll
    for (int q = 0; q < 4; ++q) {
      int lr = lrow0 + q;
      s16x4 w;
      w[0] = f2bf(r[0][q]); w[1] = f2bf(r[1][q]);
      w[2] = f2bf(r[2][q]); w[3] = f2bf(r[3][q]);
      *(s16x4*)(buf + lr * KT + ((chunk ^ ((lr >> 1) & 3)) << 3) + inner) = w;
    }
  };

  f32x4 acc[2][7];
  f32x4 zero = {0.f, 0.f, 0.f, 0.f};
  #pragma unroll
  for (int m = 0; m < 2; ++m)
    #pragma unroll
    for (int jj = 0; jj < 7; ++jj) acc[m][jj] = zero;

  loadx(0, rX);
  loadx(1, rY);
  cvtw(rX, lB[0]);
  __syncthreads();

  auto body = [&](int kt, f32x4* rNext, f32x4* rFill) {
    if (kt + 2 < 32) loadx(kt + 2, rFill);
    s16x8 a0 = *(const s16x8*)(Asrc + (size_t)(wave * 32 + l15) * 1024 + kt * 32 + l4 * 8);
    s16x8 a1 = *(const s16x8*)(Asrc + (size_t)(wave * 32 + 16 + l15) * 1024 + kt * 32 + l4 * 8);
    const short* B = lB[kt & 1];
    #pragma unroll
    for (int jj = 0; jj < 7; ++jj) {
      s16x8 bfr = *fragp(B, jj * 16 + l15, l4);
      acc[0][jj] = mfma16(a0, bfr, acc[0][jj]);
      acc[1][jj] = mfma16(a1, bfr, acc[1][jj]);
    }
    if (kt + 1 < 32) cvtw(rNext, lB[(kt + 1) & 1]);
    __syncthreads();
  };

  for (int kt = 0; kt < 32; kt += 2) {
    body(kt, rY, rX);
    body(kt + 1, rX, rY);
  }

  short* Hn = H1 + (size_t)n * P_PIX * 256;
  #pragma unroll
  for (int m = 0; m < 2; ++m) {
    int co = mb * 128 + wave * 32 + m * 16 + l4 * 4;
    f32x4 sc = *(const f32x4*)(bnbuf + co);
    f32x4 sh = *(const f32x4*)(bnbuf + 256 + co);
    #pragma unroll
    for (int jj = 0; jj < 7; ++jj) {
      if (jh && jj == 0) continue;
      int p = (jh * 6 + jj) * 16 + l15;
      if (p < P_PIX) {
        s16x4 o;
        #pragma unroll
        for (int i = 0; i < 4; ++i) {
          float y = acc[m][jj][i] + 1.0f;
          o[i] = f2bf(y * y * sc[i] + sh[i]);
        }
        *(s16x4*)(Hn + p * 256 + co) = o;
      }
    }
  }
}

// ---------------- layer 2: 3x3 pad 1, 256->256 ----------------
// grid: n(128) x mb(2) x jh(2) = 512 blocks x 512 threads, XCD-swizzled.
// Waves = 4 co-groups (wc: 32 co = 2 frags) x 2 px-groups (wp: jj 0..3 / 4..6).
// Halves per-wave LDS B-reads vs 1-frag waves (63 -> 36/27 per kt); A-frags
// double-buffered 2-deep in regs, s=0,1 hoisted before stage (vmcnt FIFO).

__global__ __launch_bounds__(512) void k_layer2(
    const short* __restrict__ H1, const short* __restrict__ W2t,
    const float* __restrict__ bnbuf, short* __restrict__ H2) {
  __shared__ __align__(16) short lB[2][NROW * KT];
  const int tid = threadIdx.x;
  const int vb = (blockIdx.x & 7) * 64 + (blockIdx.x >> 3);   // XCD swizzle (512 blocks)
  const int n = vb >> 2, mb = (vb >> 1) & 1, jh = vb & 1;
  const int lane = tid & 63, wave = tid >> 6;       // wave 0..7
  const int wc = wave & 3, wp = wave >> 2;          // wc: co-group, wp: px-group
  const int l15 = lane & 15, l4 = lane >> 4;

  if (tid < 8) {   // zero row 196 in both buffers
    int bb = tid >> 2, idx = tid & 3;
    s16x8 z = {0,0,0,0,0,0,0,0};
    *(s16x8*)(&lB[bb][196 * KT + idx * 8]) = z;
  }

  // validity masks for this wave's 4 jj tiles (jjg = wp*4 + jj, valid jjg <= 6)
  int vm[4];
  #pragma unroll
  for (int jj = 0; jj < 4; ++jj) {
    int jjg = wp * 4 + jj;
    int p = (jh * 6 + jjg) * 16 + l15;
    int m = 0;
    if (jjg < 7 && p < P_PIX) {
      int h = p / 14, w = p % 14;
      m = 2 | 16;
      if (h >= 1)  m |= 1;
      if (h < 13)  m |= 4;
      if (w >= 1)  m |= 8;
      if (w < 13)  m |= 32;
    }
    vm[jj] = m;
  }

  f32x4 acc[2][4];
  f32x4 zero = {0.f, 0.f, 0.f, 0.f};
  #pragma unroll
  for (int m = 0; m < 2; ++m)
    #pragma unroll
    for (int jj = 0; jj < 4; ++jj) acc[m][jj] = zero;

  const short* Bsrc = H1 + (size_t)n * P_PIX * 256;
  // W2t[s][co][ci]; co rows for this wave: mb*128 + wc*32 + m*16 + l15
  const short* Wbase = W2t + (size_t)(mb * 128 + wc * 32 + l15) * 256 + l4 * 8;

  stage(Bsrc, 256, 0, lB[0], P_PIX, P_PIX - 1, tid, 512);
  __syncthreads();

  for (int kt = 0; kt < 8; ++kt) {
    const int ko = kt * 32;
    // hoist s=0 and s=1 A-frags ahead of the stage (oldest in vmcnt FIFO)
    s16x8 aE0 = *(const s16x8*)(Wbase + (size_t)0 * 65536 + ko);
    s16x8 aE1 = *(const s16x8*)(Wbase + (size_t)0 * 65536 + 4096 + ko);
    s16x8 aO0 = *(const s16x8*)(Wbase + (size_t)1 * 65536 + ko);
    s16x8 aO1 = *(const s16x8*)(Wbase + (size_t)1 * 65536 + 4096 + ko);
    if (kt < 7)
      stage(Bsrc, 256, (kt + 1) * 32, lB[(kt + 1) & 1], P_PIX, P_PIX - 1, tid, 512);
    const short* B = lB[kt & 1];
    #pragma unroll
    for (int s = 0; s < 9; ++s) {
      s16x8 a0 = (s & 1) ? aO0 : aE0;
      s16x8 a1 = (s & 1) ? aO1 : aE1;
      if (s + 2 <= 8) {   // refill the buffer just consumed 2 s-steps ahead
        if (s & 1) {
          aO0 = *(const s16x8*)(Wbase + (size_t)(s + 2) * 65536 + ko);
          aO1 = *(const s16x8*)(Wbase + (size_t)(s + 2) * 65536 + 4096 + ko);
        } else {
          aE0 = *(const s16x8*)(Wbase + (size_t)(s + 2) * 65536 + ko);
          aE1 = *(const s16x8*)(Wbase + (size_t)(s + 2) * 65536 + 4096 + ko);
        }
      }
      const int dy = s / 3, dx = s % 3;
      const int doff = (dy - 1) * 14 + (dx - 1);
      #pragma unroll
      for (int jj = 0; jj < 4; ++jj) {
        if (wp == 1 && jj == 3) continue;     // jjg=7 doesn't exist
        int jjg = wp * 4 + jj;
        int p = (jh * 6 + jjg) * 16 + l15;
        bool valid = ((vm[jj] >> dy) & 1) && ((vm[jj] >> (3 + dx)) & 1);
        int row = valid ? (p + doff) : 196;
        s16x8 bfr = *fragp(B, row, l4);
        acc[0][jj] = mfma16(a0, bfr, acc[0][jj]);
        acc[1][jj] = mfma16(a1, bfr, acc[1][jj]);
      }
    }
    __syncthreads();
  }

  short* Hn = H2 + (size_t)n * P_PIX * 256;
  #pragma unroll
  for (int m = 0; m < 2; ++m) {
    int co = mb * 128 + wc * 32 + m * 16 + l4 * 4;
    f32x4 sc = *(const f32x4*)(bnbuf + 512 + co);
    f32x4 sh = *(const f32x4*)(bnbuf + 768 + co);
    #pragma unroll
    for (int jj = 0; jj < 4; ++jj) {
      if (wp == 1 && jj == 3) continue;
      int jjg = wp * 4 + jj;
      if (jh && jjg == 0) continue;           // overlap tile owned by jh=0
      int p = (jh * 6 + jjg) * 16 + l15;
      if (p < P_PIX) {
        s16x4 o;
        #pragma unroll
        for (int i = 0; i < 4; ++i) {
          float y = acc[m][jj][i] + 1.0f;
          o[i] = f2bf(y * y * sc[i] + sh[i]);
        }
        *(s16x4*)(Hn + p * 256 + co) = o;
      }
    }
  }
}

// ---------------- layer 3: 1x1, 256->1024, + residual ----------------
// grid n(128) x mb(16), XCD-swizzled: full-image tiles (64 co x 196 px).
// x/out accesses are whole 784-B contiguous co-rows. LDS 27.1 KB -> 6 blocks/CU.

__global__ __launch_bounds__(256) void k_layer3(
    const short* __restrict__ H2, const short* __restrict__ W3b,
    const float* __restrict__ bnbuf, const float* __restrict__ x,
    float* __restrict__ out) {
  __shared__ __align__(16) char smem[27136];
  short* const lB0 = (short*)smem;            // [208 rows][KT]
  short* const lB1 = lB0 + NROW * KT;         // 13312 B each
  float* const eb = (float*)smem;             // [32 co][212 p] fp32 epilogue buffer

  const int tid = threadIdx.x;
  const int vb = (blockIdx.x & 7) * 256 + (blockIdx.x >> 3);  // XCD swizzle (2048 blocks)
  const int n = vb >> 4, mb = vb & 15;
  const int lane = tid & 63, wave = tid >> 6;
  const int l15 = lane & 15, l4 = lane >> 4;

  const short* Asrc = W3b + (size_t)(mb * 64) * 256;
  const short* Bsrc = H2 + (size_t)n * P_PIX * 256;

  f32x4 acc[13];
  f32x4 zero = {0.f, 0.f, 0.f, 0.f};
  #pragma unroll
  for (int j = 0; j < 13; ++j) acc[j] = zero;

  stage(Bsrc, 256, 0, lB0, NROW, P_PIX - 1, tid, 256);
  __syncthreads();

  for (int kt = 0; kt < 8; ++kt) {
    s16x8 a = *(const s16x8*)(Asrc + (size_t)(wave * 16 + l15) * 256 + kt * 32 + l4 * 8);
    if (kt < 7)
      stage(Bsrc, 256, (kt + 1) * 32, ((kt + 1) & 1) ? lB1 : lB0, NROW, P_PIX - 1, tid, 256);
    const short* B = (kt & 1) ? lB1 : lB0;
    #pragma unroll
    for (int j = 0; j < 13; ++j) {
      // j=12 rows 196..207 garbage -> output cols p>=196, never read back
      s16x8 bfr = *fragp(B, j * 16 + l15, l4);
      acc[j] = mfma16(a, bfr, acc[j]);
    }
    __syncthreads();
  }

  // epilogue: two co-halves; dump acc -> LDS, then full-row vectorized x/out
  const int co_r = tid >> 3;            // 0..31
  const int pcb  = tid & 7;
  #pragma unroll
  for (int h = 0; h < 2; ++h) {
    __syncthreads();
    if ((wave >> 1) == h) {
      const int co_l = (wave & 1) * 16 + l4 * 4;
      #pragma unroll
      for (int j = 0; j < 13; ++j) {
        const int p = j * 16 + l15;
        #pragma unroll
        for (int i = 0; i < 4; ++i)
          eb[(co_l + i) * 212 + p] = acc[j][i];
      }
    }
    __syncthreads();
    const int co_g = mb * 64 + h * 32 + co_r;
    const float scv = bnbuf[1024 + co_g];
    const float shv = bnbuf[2048 + co_g];
    const size_t rowbase = ((size_t)(n * 1024 + co_g)) * P_PIX;
    #pragma unroll
    for (int pass = 0; pass < 7; ++pass) {
      const int pc = pcb + pass * 8;
      if (pc < 49) {                         // 49*4 = 196 px exactly
        f32x4 v = *(const f32x4*)(eb + co_r * 212 + pc * 4);
        const size_t idx = rowbase + pc * 4;
        f32x4 xv = *(const f32x4*)(x + idx);
        f32x4 o;
        #pragma unroll
        for (int k = 0; k < 4; ++k) {
          float y = v[k] + 1.0f;
          o[k] = y * y * scv + shv + xv[k];
        }
        *(f32x4*)(out + idx) = o;
      }
    }
  }
}

// ---------------- launch ----------------

extern "C" void kernel_launch(void* const* d_in, const int* in_sizes, int n_in,
                              void* d_out, int out_size, void* d_ws, size_t ws_size,
                              hipStream_t stream) {
  (void)in_sizes; (void)n_in; (void)out_size; (void)ws_size;
  const float* x  = (const float*)d_in[0];
  const float* w1 = (const float*)d_in[1];
  const float* w2 = (const float*)d_in[2];
  const float* w3 = (const float*)d_in[3];
  const float* g1 = (const float*)d_in[4];
  const float* b1 = (const float*)d_in[5];
  const float* m1 = (const float*)d_in[6];
  const float* v1 = (const float*)d_in[7];
  const float* g2 = (const float*)d_in[8];
  const float* b2 = (const float*)d_in[9];
  const float* m2 = (const float*)d_in[10];
  const float* v2 = (const float*)d_in[11];
  const float* g3 = (const float*)d_in[12];
  const float* b3 = (const float*)d_in[13];
  const float* m3 = (const float*)d_in[14];
  const float* v3 = (const float*)d_in[15];

  char* ws = (char*)d_ws;
  short* W1b   = (short*)(ws + 0);          // 524288
  short* W2t   = (short*)(ws + 524288);     // 1179648
  short* W3b   = (short*)(ws + 1703936);    // 524288
  float* bnbuf = (float*)(ws + 2228224);    // 12288
  short* H1    = (short*)(ws + 2240512);    // 12845056
  short* H2    = (short*)(ws + 15085568);   // 12845056

  k_prep<<<1094, 256, 0, stream>>>(w1, w2, w3,
                                   g1, b1, m1, v1, g2, b2, m2, v2, g3, b3, m3, v3,
                                   bnbuf, W1b, W2t, W3b);
  k_layer1<<<512, 256, 0, stream>>>(x, W1b, bnbuf, H1);
  k_layer2<<<512, 512, 0, stream>>>(H1, W2t, bnbuf, H2);
  k_layer3<<<2048, 256, 0, stream>>>(H2, W3b, bnbuf, x, (float*)d_out);
}

// Round 13
// 135.582 us; speedup vs baseline: 1.2619x; 1.2619x over previous
//
#include <hip/hip_runtime.h>

using f32x4 = __attribute__((ext_vector_type(4))) float;
using s16x8 = __attribute__((ext_vector_type(8))) short;
using s16x4 = __attribute__((ext_vector_type(4))) short;

#define P_PIX 196
#define NPIX_ALL (128 * 196)   // 25088
#define NROW  208
#define KT    32               // shorts per LDS row = 64 B = 4 chunks of 16 B

static __device__ __forceinline__ short f2bf(float f) {
  union { float f; unsigned u; } a; a.f = f;
  unsigned u = a.u;
  u += 0x7fffu + ((u >> 16) & 1u);   // RNE
  return (short)(u >> 16);
}

static __device__ __forceinline__ f32x4 mfma16(s16x8 a, s16x8 b, f32x4 c) {
  return __builtin_amdgcn_mfma_f32_16x16x32_bf16(a, b, c, 0, 0, 0);
}

static __device__ __forceinline__ void gload16(const short* g, short* l) {
  __builtin_amdgcn_global_load_lds(
      (const __attribute__((address_space(1))) unsigned int*)(g),
      (__attribute__((address_space(3))) unsigned int*)(l), 16, 0, 0);
}

// swizzled 16B-fragment pointer: chunk = l4 ^ ((row>>1)&3)   (KT=32 layout)
static __device__ __forceinline__ const s16x8* fragp(const short* buf, int row, int l4) {
  return (const s16x8*)(buf + row * KT + ((l4 ^ ((row >> 1) & 3)) << 3));
}

// stage rows x 32 shorts into LDS; dest linear, source chunk pre-swizzled.
static __device__ __forceinline__ void stage(const short* __restrict__ src, int srcK,
                                             int k0, short* dst, int rows, int rmax,
                                             int tid, int nthr) {
  for (int t = tid; t < rows * 4; t += nthr) {
    int r = t >> 2, c = t & 3;
    int rr = r < rmax ? r : rmax;
    int cs = c ^ ((r >> 1) & 3);
    gload16(src + (size_t)rr * srcK + k0 + cs * 8, dst + t * 8);
  }
}

// ---------------- merged prep: w1/w3 cvt, w2 transpose, bn fold ----------------

__global__ void k_prep(const float* __restrict__ w1, const float* __restrict__ w2,
                       const float* __restrict__ w3,
                       const float* g1, const float* b1, const float* m1, const float* v1,
                       const float* g2, const float* b2, const float* m2, const float* v2,
                       const float* g3, const float* b3, const float* m3, const float* v3,
                       float* bn, short* W1b, short* W2t, short* W3b) {
  int i = blockIdx.x * 256 + threadIdx.x;
  if (i < 65536) {
    f32x4 v = *(const f32x4*)(w1 + i * 4);
    s16x4 o;
    o[0] = f2bf(v[0]); o[1] = f2bf(v[1]); o[2] = f2bf(v[2]); o[3] = f2bf(v[3]);
    *(s16x4*)(W1b + i * 4) = o;
  } else if (i < 131072) {
    int q = i - 65536;
    f32x4 v = *(const f32x4*)(w3 + q * 4);
    s16x4 o;
    o[0] = f2bf(v[0]); o[1] = f2bf(v[1]); o[2] = f2bf(v[2]); o[3] = f2bf(v[3]);
    *(s16x4*)(W3b + q * 4) = o;
  } else if (i < 278528) {
    int q = (i - 131072) * 4;
    s16x4 o;
    #pragma unroll
    for (int k = 0; k < 4; ++k) {
      int idx = q + k;
      int s = idx >> 16, rem = idx & 65535;
      int co = rem >> 8, ci = rem & 255;
      o[k] = f2bf(w2[(co * 256 + ci) * 9 + s]);
    }
    *(s16x4*)(W2t + q) = o;
  } else if (i < 280064) {
    int t = i - 278528;
    if (t < 256) {
      float inv = g1[t] * rsqrtf(v1[t] + 1e-5f);
      bn[t] = inv; bn[256 + t] = b1[t] - m1[t] * inv;
    } else if (t < 512) {
      int c = t - 256;
      float inv = g2[c] * rsqrtf(v2[c] + 1e-5f);
      bn[512 + c] = inv; bn[768 + c] = b2[c] - m2[c] * inv;
    } else {
      int c = t - 512;
      float inv = g3[c] * rsqrtf(v3[c] + 1e-5f);
      bn[1024 + c] = inv; bn[2048 + c] = b3[c] - m3[c] * inv;
    }
  }
}

// ---------------- layer 1: 1x1, 1024->256, fused fp32-x transpose+cvt ----------------
// grid: n(128) x mb(2) x jh(2), XCD-swizzled. A-frags from global (W1 L2-resident).

__global__ __launch_bounds__(256) void k_layer1(
    const float* __restrict__ x, const short* __restrict__ W1b,
    const float* __restrict__ bnbuf, short* __restrict__ H1) {
  __shared__ __align__(16) short lB[2][128 * KT];
  const int tid = threadIdx.x;
  const int vb = (blockIdx.x & 7) * 64 + (blockIdx.x >> 3);   // XCD swizzle (512 blocks)
  const int n = vb >> 2, mb = (vb >> 1) & 1, jh = vb & 1;
  const int lane = tid & 63, wave = tid >> 6;
  const int l15 = lane & 15, l4 = lane >> 4;

  if (jh == 1 && tid < 96) {
    int bb = tid / 48, idx = tid % 48;
    s16x8 z = {0,0,0,0,0,0,0,0};
    *(s16x8*)(&lB[bb][100 * KT + idx * 8]) = z;
  }

  const float* xs = x + (size_t)n * 1024 * P_PIX;
  const short* Asrc = W1b + (size_t)(mb * 128) * 1024;

  const int npg = jh ? 25 : 28;
  const int pgbase = jh ? 24 : 0;
  const bool act = tid < npg * 8;
  const int pg = pgbase + (act ? tid % npg : 0);
  const int kg = act ? tid / npg : 0;
  const int lrow0 = pg * 4 - jh * 96;

  f32x4 rX[4], rY[4];
  auto loadx = [&](int kt, f32x4* r) {
    if (!act) return;
    const float* sp = xs + (size_t)(kt * 32 + kg * 4) * P_PIX + pg * 4;
    r[0] = *(const f32x4*)sp;
    r[1] = *(const f32x4*)(sp + P_PIX);
    r[2] = *(const f32x4*)(sp + 2 * P_PIX);
    r[3] = *(const f32x4*)(sp + 3 * P_PIX);
  };
  auto cvtw = [&](const f32x4* r, short* buf) {
    if (!act) return;
    int chunk = kg >> 1, inner = (kg & 1) * 4;
    #pragma unroll
    for (int q = 0; q < 4; ++q) {
      int lr = lrow0 + q;
      s16x4 w;
      w[0] = f2bf(r[0][q]); w[1] = f2bf(r[1][q]);
      w[2] = f2bf(r[2][q]); w[3] = f2bf(r[3][q]);
      *(s16x4*)(buf + lr * KT + ((chunk ^ ((lr >> 1) & 3)) << 3) + inner) = w;
    }
  };

  f32x4 acc[2][7];
  f32x4 zero = {0.f, 0.f, 0.f, 0.f};
  #pragma unroll
  for (int m = 0; m < 2; ++m)
    #pragma unroll
    for (int jj = 0; jj < 7; ++jj) acc[m][jj] = zero;

  loadx(0, rX);
  loadx(1, rY);
  cvtw(rX, lB[0]);
  __syncthreads();

  auto body = [&](int kt, f32x4* rNext, f32x4* rFill) {
    if (kt + 2 < 32) loadx(kt + 2, rFill);
    s16x8 a0 = *(const s16x8*)(Asrc + (size_t)(wave * 32 + l15) * 1024 + kt * 32 + l4 * 8);
    s16x8 a1 = *(const s16x8*)(Asrc + (size_t)(wave * 32 + 16 + l15) * 1024 + kt * 32 + l4 * 8);
    const short* B = lB[kt & 1];
    #pragma unroll
    for (int jj = 0; jj < 7; ++jj) {
      s16x8 bfr = *fragp(B, jj * 16 + l15, l4);
      acc[0][jj] = mfma16(a0, bfr, acc[0][jj]);
      acc[1][jj] = mfma16(a1, bfr, acc[1][jj]);
    }
    if (kt + 1 < 32) cvtw(rNext, lB[(kt + 1) & 1]);
    __syncthreads();
  };

  for (int kt = 0; kt < 32; kt += 2) {
    body(kt, rY, rX);
    body(kt + 1, rX, rY);
  }

  short* Hn = H1 + (size_t)n * P_PIX * 256;
  #pragma unroll
  for (int m = 0; m < 2; ++m) {
    int co = mb * 128 + wave * 32 + m * 16 + l4 * 4;
    f32x4 sc = *(const f32x4*)(bnbuf + co);
    f32x4 sh = *(const f32x4*)(bnbuf + 256 + co);
    #pragma unroll
    for (int jj = 0; jj < 7; ++jj) {
      if (jh && jj == 0) continue;
      int p = (jh * 6 + jj) * 16 + l15;
      if (p < P_PIX) {
        s16x4 o;
        #pragma unroll
        for (int i = 0; i < 4; ++i) {
          float y = acc[m][jj][i] + 1.0f;
          o[i] = f2bf(y * y * sc[i] + sh[i]);
        }
        *(s16x4*)(Hn + p * 256 + co) = o;
      }
    }
  }
}

// ---------------- layer 2: 3x3 pad 1, 256->256 — BARRIER-FREE ----------------
// grid: n(128) x jh(2) = 256 blocks x 512 threads, XCD-swizzled (1 block/CU).
// Full-K H1[n] tile (196x256 bf16 = 100 KB) staged to LDS ONCE, one barrier,
// then the whole kt/s/jj loop is barrier-free (LDS + L2 reads only).
// 8 waves x 2 co-frags = 256 co; each wave does all 7 px tiles.
// LDS layout: row*256 shorts, physical chunk pc holds logical pc^(row&7)
// (XOR swizzle -> 2-way bank aliasing on ds_read_b128).

__global__ __launch_bounds__(512) void k_layer2(
    const short* __restrict__ H1, const short* __restrict__ W2t,
    const float* __restrict__ bnbuf, short* __restrict__ H2) {
  __shared__ __align__(16) short lB[197 * 256];   // 100,864 B
  const int tid = threadIdx.x;
  const int vb = (blockIdx.x & 7) * 32 + (blockIdx.x >> 3);   // XCD swizzle (256 blocks)
  const int n = vb >> 1, jh = vb & 1;
  const int lane = tid & 63, wave = tid >> 6;       // wave 0..7 = co-group
  const int l15 = lane & 15, l4 = lane >> 4;

  // stage full tile: LDS[row][pc] = H1n[row][pc ^ (row&7)]
  const short* Bsrc = H1 + (size_t)n * P_PIX * 256;
  for (int t = tid; t < 6272; t += 512) {           // 196 rows * 32 chunks
    int row = t >> 5, pc = t & 31;
    int lc = pc ^ (row & 7);
    gload16(Bsrc + row * 256 + lc * 8, lB + t * 8);
  }
  if (tid < 32) {                                   // zero row 196 (all chunks)
    s16x8 z = {0,0,0,0,0,0,0,0};
    *(s16x8*)(&lB[196 * 256 + tid * 8]) = z;
  }

  int vm[7];
  #pragma unroll
  for (int jj = 0; jj < 7; ++jj) {
    int p = (jh * 6 + jj) * 16 + l15;
    int m = 0;
    if (p < P_PIX) {
      int h = p / 14, w = p % 14;
      m = 2 | 16;
      if (h >= 1)  m |= 1;
      if (h < 13)  m |= 4;
      if (w >= 1)  m |= 8;
      if (w < 13)  m |= 32;
    }
    vm[jj] = m;
  }

  f32x4 acc[2][7];
  f32x4 zero = {0.f, 0.f, 0.f, 0.f};
  #pragma unroll
  for (int m = 0; m < 2; ++m)
    #pragma unroll
    for (int jj = 0; jj < 7; ++jj) acc[m][jj] = zero;

  auto LA = [&](int kt, int s, int m) -> s16x8 {
    return *(const s16x8*)(W2t +
        (size_t)((s * 256 + wave * 32 + m * 16 + l15) * 256) + kt * 32 + l4 * 8);
  };

  __syncthreads();   // the ONLY barrier: full tile + zero row visible

  s16x8 aC0 = LA(0, 0, 0), aC1 = LA(0, 0, 1);
  for (int kt = 0; kt < 8; ++kt) {
    const int lcb = kt << 2;                        // logical chunk base
    #pragma unroll
    for (int s = 0; s < 9; ++s) {
      s16x8 aN0 = aC0, aN1 = aC1;
      const int s1 = (s == 8) ? 0 : s + 1;
      const int kt1 = (s == 8) ? kt + 1 : kt;
      if (kt1 < 8) { aN0 = LA(kt1, s1, 0); aN1 = LA(kt1, s1, 1); }   // prefetch
      const int dy = s / 3, dx = s % 3;
      const int doff = (dy - 1) * 14 + (dx - 1);
      #pragma unroll
      for (int jj = 0; jj < 7; ++jj) {
        int p = (jh * 6 + jj) * 16 + l15;
        bool valid = ((vm[jj] >> dy) & 1) && ((vm[jj] >> (3 + dx)) & 1);
        int row = valid ? (p + doff) : 196;
        int pc = (lcb | l4) ^ (row & 7);
        s16x8 bfr = *(const s16x8*)(lB + row * 256 + (pc << 3));
        acc[0][jj] = mfma16(aC0, bfr, acc[0][jj]);
        acc[1][jj] = mfma16(aC1, bfr, acc[1][jj]);
      }
      aC0 = aN0; aC1 = aN1;
    }
  }

  short* Hn = H2 + (size_t)n * P_PIX * 256;
  #pragma unroll
  for (int m = 0; m < 2; ++m) {
    int co = wave * 32 + m * 16 + l4 * 4;
    f32x4 sc = *(const f32x4*)(bnbuf + 512 + co);
    f32x4 sh = *(const f32x4*)(bnbuf + 768 + co);
    #pragma unroll
    for (int jj = 0; jj < 7; ++jj) {
      if (jh && jj == 0) continue;           // overlap tile owned by jh=0
      int p = (jh * 6 + jj) * 16 + l15;
      if (p < P_PIX) {
        s16x4 o;
        #pragma unroll
        for (int i = 0; i < 4; ++i) {
          float y = acc[m][jj][i] + 1.0f;
          o[i] = f2bf(y * y * sc[i] + sh[i]);
        }
        *(s16x4*)(Hn + p * 256 + co) = o;
      }
    }
  }
}

// ---------------- layer 3: 1x1, 256->1024, + residual ----------------
// grid n(128) x mb(16), XCD-swizzled: full-image tiles (64 co x 196 px).
// x/out accesses are whole 784-B contiguous co-rows. LDS 27.1 KB -> 6 blocks/CU.

__global__ __launch_bounds__(256) void k_layer3(
    const short* __restrict__ H2, const short* __restrict__ W3b,
    const float* __restrict__ bnbuf, const float* __restrict__ x,
    float* __restrict__ out) {
  __shared__ __align__(16) char smem[27136];
  short* const lB0 = (short*)smem;            // [208 rows][KT]
  short* const lB1 = lB0 + NROW * KT;         // 13312 B each
  float* const eb = (float*)smem;             // [32 co][212 p] fp32 epilogue buffer

  const int tid = threadIdx.x;
  const int vb = (blockIdx.x & 7) * 256 + (blockIdx.x >> 3);  // XCD swizzle (2048 blocks)
  const int n = vb >> 4, mb = vb & 15;
  const int lane = tid & 63, wave = tid >> 6;
  const int l15 = lane & 15, l4 = lane >> 4;

  const short* Asrc = W3b + (size_t)(mb * 64) * 256;
  const short* Bsrc = H2 + (size_t)n * P_PIX * 256;

  f32x4 acc[13];
  f32x4 zero = {0.f, 0.f, 0.f, 0.f};
  #pragma unroll
  for (int j = 0; j < 13; ++j) acc[j] = zero;

  stage(Bsrc, 256, 0, lB0, NROW, P_PIX - 1, tid, 256);
  __syncthreads();

  for (int kt = 0; kt < 8; ++kt) {
    s16x8 a = *(const s16x8*)(Asrc + (size_t)(wave * 16 + l15) * 256 + kt * 32 + l4 * 8);
    if (kt < 7)
      stage(Bsrc, 256, (kt + 1) * 32, ((kt + 1) & 1) ? lB1 : lB0, NROW, P_PIX - 1, tid, 256);
    const short* B = (kt & 1) ? lB1 : lB0;
    #pragma unroll
    for (int j = 0; j < 13; ++j) {
      // j=12 rows 196..207 garbage -> output cols p>=196, never read back
      s16x8 bfr = *fragp(B, j * 16 + l15, l4);
      acc[j] = mfma16(a, bfr, acc[j]);
    }
    __syncthreads();
  }

  // epilogue: two co-halves; dump acc -> LDS, then full-row vectorized x/out
  const int co_r = tid >> 3;            // 0..31
  const int pcb  = tid & 7;
  #pragma unroll
  for (int h = 0; h < 2; ++h) {
    __syncthreads();
    if ((wave >> 1) == h) {
      const int co_l = (wave & 1) * 16 + l4 * 4;
      #pragma unroll
      for (int j = 0; j < 13; ++j) {
        const int p = j * 16 + l15;
        #pragma unroll
        for (int i = 0; i < 4; ++i)
          eb[(co_l + i) * 212 + p] = acc[j][i];
      }
    }
    __syncthreads();
    const int co_g = mb * 64 + h * 32 + co_r;
    const float scv = bnbuf[1024 + co_g];
    const float shv = bnbuf[2048 + co_g];
    const size_t rowbase = ((size_t)(n * 1024 + co_g)) * P_PIX;
    #pragma unroll
    for (int pass = 0; pass < 7; ++pass) {
      const int pc = pcb + pass * 8;
      if (pc < 49) {                         // 49*4 = 196 px exactly
        f32x4 v = *(const f32x4*)(eb + co_r * 212 + pc * 4);
        const size_t idx = rowbase + pc * 4;
        f32x4 xv = *(const f32x4*)(x + idx);
        f32x4 o;
        #pragma unroll
        for (int k = 0; k < 4; ++k) {
          float y = v[k] + 1.0f;
          o[k] = y * y * scv + shv + xv[k];
        }
        *(f32x4*)(out + idx) = o;
      }
    }
  }
}

// ---------------- launch ----------------

extern "C" void kernel_launch(void* const* d_in, const int* in_sizes, int n_in,
                              void* d_out, int out_size, void* d_ws, size_t ws_size,
                              hipStream_t stream) {
  (void)in_sizes; (void)n_in; (void)out_size; (void)ws_size;
  const float* x  = (const float*)d_in[0];
  const float* w1 = (const float*)d_in[1];
  const float* w2 = (const float*)d_in[2];
  const float* w3 = (const float*)d_in[3];
  const float* g1 = (const float*)d_in[4];
  const float* b1 = (const float*)d_in[5];
  const float* m1 = (const float*)d_in[6];
  const float* v1 = (const float*)d_in[7];
  const float* g2 = (const float*)d_in[8];
  const float* b2 = (const float*)d_in[9];
  const float* m2 = (const float*)d_in[10];
  const float* v2 = (const float*)d_in[11];
  const float* g3 = (const float*)d_in[12];
  const float* b3 = (const float*)d_in[13];
  const float* m3 = (const float*)d_in[14];
  const float* v3 = (const float*)d_in[15];

  char* ws = (char*)d_ws;
  short* W1b   = (short*)(ws + 0);          // 524288
  short* W2t   = (short*)(ws + 524288);     // 1179648
  short* W3b   = (short*)(ws + 1703936);    // 524288
  float* bnbuf = (float*)(ws + 2228224);    // 12288
  short* H1    = (short*)(ws + 2240512);    // 12845056
  short* H2    = (short*)(ws + 15085568);   // 12845056

  k_prep<<<1094, 256, 0, stream>>>(w1, w2, w3,
                                   g1, b1, m1, v1, g2, b2, m2, v2, g3, b3, m3, v3,
                                   bnbuf, W1b, W2t, W3b);
  k_layer1<<<512, 256, 0, stream>>>(x, W1b, bnbuf, H1);
  k_layer2<<<256, 512, 0, stream>>>(H1, W2t, bnbuf, H2);
  k_layer3<<<2048, 256, 0, stream>>>(H2, W3b, bnbuf, x, (float*)d_out);
}